// Round 2
// baseline (369.566 us; speedup 1.0000x reference)
//
#include <hip/hip_runtime.h>

// Problem constants
#define Cn   192      // channels = 3*D
#define Dn   64       // hidden
#define G3   192      // 3*D gates
#define HWn  16384    // H*W per batch
#define NSp  131072L  // B*H*W total spatial
#define Tn   128

typedef unsigned short u16;
typedef __attribute__((ext_vector_type(8))) short s8v;   // 8 bf16 (4 VGPRs) MFMA A/B frag
typedef __attribute__((ext_vector_type(4))) float f4v;   // MFMA C/D frag

__device__ __forceinline__ float bf2f(u16 u){
  union { unsigned int i; float f; } v; v.i = ((unsigned int)u) << 16; return v.f;
}
__device__ __forceinline__ u16 f2bf(float f){
  union { float f; unsigned int u; } v; v.f = f;
  return (u16)((v.u + 0x7FFFu + ((v.u >> 16) & 1u)) >> 16);  // RNE
}
__device__ __forceinline__ s8v load8_f32_as_bf16(const float* __restrict__ p){
  s8v r;
  #pragma unroll
  for (int i = 0; i < 8; i++) r[i] = (short)f2bf(p[i]);
  return r;
}
__device__ __forceinline__ float sigf(float x){ return 1.f / (1.f + __expf(-x)); }
__device__ __forceinline__ float tanh_fast(float x){ return 2.f / (1.f + __expf(-2.f * x)) - 1.f; } // saturating

// ---------------------------------------------------------------------------
// Kernel 0: W_comb = W_ih @ Wi  (store bf16), b_comb = W_ih @ bi + b_ih (fp32)
// ---------------------------------------------------------------------------
__global__ __launch_bounds__(256) void k_wcomb(const float* __restrict__ Wi, const float* __restrict__ bi,
                                               const float* __restrict__ W_ih, const float* __restrict__ b_ih,
                                               u16* __restrict__ wcomb, float* __restrict__ bcomb){
  if (blockIdx.x < 144) {
    int idx = blockIdx.x * 256 + threadIdx.x;   // 36864 = 192*192
    int g = idx / 192, c = idx - g * 192;
    float acc = 0.f;
    #pragma unroll 8
    for (int d = 0; d < 64; d++)
      acc += W_ih[g * 64 + d] * Wi[d * 192 + c];
    wcomb[g * 192 + c] = f2bf(acc);
  } else if (threadIdx.x < 192) {
    int g = threadIdx.x;
    float acc = b_ih[g];
    for (int d = 0; d < 64; d++)
      acc += W_ih[g * 64 + d] * bi[d];
    bcomb[g] = acc;
  }
}

// ---------------------------------------------------------------------------
// Kernel 1: G[s][g] = b_comb[g] + sum_c x[c][s] * W_comb[g][c]   (bf16 out)
// MFMA: M=64 spatial/block, N=192 gates, K=192 channels. B-frags (W_comb rows)
// in registers; A staged via LDS transpose of x (fp32 -> bf16 on the way in).
// ---------------------------------------------------------------------------
__global__ __launch_bounds__(256) void k_gates(const float* __restrict__ x, const u16* __restrict__ wcomb,
                                               const float* __restrict__ bcomb, u16* __restrict__ G){
  __shared__ u16 xT[64][200];                 // [spatial][channel], row = 400 B (16B-aligned, padded)
  const int tid = threadIdx.x;
  const int wave = tid >> 6, lane = tid & 63;
  const int col = lane & 15, kq = lane >> 4;
  const long s0 = (long)blockIdx.x * 64;
  const int b   = (int)(s0 >> 14);
  const int hw0 = (int)(s0 & 16383);

  // B-fragments: wave handles gates [48w, 48w+48): 3 n-tiles x 6 k-chunks
  s8v bfrag[3][6];
  #pragma unroll
  for (int j = 0; j < 3; j++) {
    int g = wave * 48 + j * 16 + col;
    #pragma unroll
    for (int kc = 0; kc < 6; kc++)
      bfrag[j][kc] = *(const s8v*)(wcomb + g * 192 + kc * 32 + kq * 8);
  }

  // Stage x tile transposed: float4 (4 consecutive spatial) per iter, cvt bf16
  for (int idx = tid; idx < 192 * 16; idx += 256) {
    int c  = idx >> 4;
    int s4 = (idx & 15) * 4;
    float4 v = *(const float4*)(x + (long)(b * 192 + c) * HWn + hw0 + s4);
    xT[s4 + 0][c] = f2bf(v.x); xT[s4 + 1][c] = f2bf(v.y);
    xT[s4 + 2][c] = f2bf(v.z); xT[s4 + 3][c] = f2bf(v.w);
  }
  __syncthreads();

  f4v acc[4][3];
  #pragma unroll
  for (int m = 0; m < 4; m++)
    #pragma unroll
    for (int j = 0; j < 3; j++) acc[m][j] = (f4v){0.f, 0.f, 0.f, 0.f};

  #pragma unroll
  for (int kc = 0; kc < 6; kc++) {
    #pragma unroll
    for (int m = 0; m < 4; m++) {
      s8v a = *(const s8v*)(&xT[m * 16 + col][kc * 32 + kq * 8]);
      #pragma unroll
      for (int j = 0; j < 3; j++)
        acc[m][j] = __builtin_amdgcn_mfma_f32_16x16x32_bf16(a, bfrag[j][kc], acc[m][j], 0, 0, 0);
    }
  }

  // Epilogue: bias + store (C layout: col=lane&15 -> gate, row=4*kq+reg -> spatial)
  #pragma unroll
  for (int j = 0; j < 3; j++) {
    int g = wave * 48 + j * 16 + col;
    float bias = bcomb[g];
    #pragma unroll
    for (int m = 0; m < 4; m++) {
      #pragma unroll
      for (int r = 0; r < 4; r++) {
        long srow = s0 + m * 16 + kq * 4 + r;
        G[srow * 192 + g] = f2bf(acc[m][j][r] + bias);
      }
    }
  }
}

// ---------------------------------------------------------------------------
// Kernel 2: directional GRU scans. 1 block = 16 sequences of one direction.
// Per step: HG(16x192) = h(16x64) @ W_hh^T via MFMA (W_hh B-frags in regs,
// b_hh in acc init) -> LDS -> gate phase (h_old in regs) -> h back to LDS
// (bf16 A-layout) + streamed to Hall[dir].
// ---------------------------------------------------------------------------
__global__ __launch_bounds__(256) void k_scan(const u16* __restrict__ G, const float* __restrict__ W_hh,
                                              const float* __restrict__ b_hh, u16* __restrict__ Hall){
  __shared__ u16  ha[16][72];      // h bf16, A-frag layout [seq][d], row 144 B
  __shared__ float hgl[16][196];   // HG fp32 [seq][gate], row 784 B (16B-aligned)
  const int tid = threadIdx.x;
  const int wave = tid >> 6, lane = tid & 63;
  const int col = lane & 15, kq = lane >> 4;
  const int dir  = blockIdx.x >> 6;   // 0:right 1:down 2:left 3:up
  const int sblk = blockIdx.x & 63;

  // W_hh B-fragments (persistent, fp32 -> bf16) + bias-in-accumulator
  s8v bfrag0[3], bfrag1[3];
  f4v biasf[3];
  #pragma unroll
  for (int j = 0; j < 3; j++) {
    int g = wave * 48 + j * 16 + col;
    bfrag0[j] = load8_f32_as_bf16(W_hh + g * 64 + kq * 8);
    bfrag1[j] = load8_f32_as_bf16(W_hh + g * 64 + 32 + kq * 8);
    float bb = b_hh[g];
    biasf[j] = (f4v){bb, bb, bb, bb};
  }

  // gate-phase identity: thread -> (seq slot, 4 consecutive d)
  const int gs = tid >> 4;
  const int d0 = (tid & 15) * 4;
  const int seq = sblk * 16 + gs;          // 0..1023
  const int b = seq >> 7, a = seq & 127;   // a = h (row dirs) or w (col dirs)
  long base; int stride;
  if ((dir & 1) == 0) { base = ((long)(b * 128 + a)) * 128; stride = 1;   } // scan over w
  else                { base = (long)b * 16384 + a;         stride = 128; } // scan over h
  const int rev = dir >> 1;
  u16* __restrict__ Hs = Hall + (long)dir * (NSp * 64);

  for (int i = tid; i < 16 * 72; i += 256) ((u16*)ha)[i] = 0;   // h0 = 0
  float hold[4] = {0.f, 0.f, 0.f, 0.f};

  // prefetch xg for t=0
  uint2 xr, xz, xn;
  {
    int tp = rev ? 127 : 0;
    const u16* gp = G + (base + (long)tp * stride) * 192 + d0;
    xr = *(const uint2*)(gp);
    xz = *(const uint2*)(gp + 64);
    xn = *(const uint2*)(gp + 128);
  }
  __syncthreads();

  for (int t = 0; t < 128; t++) {
    // prefetch xg for t+1 (hidden under MFMA phase + barrier)
    uint2 nxr, nxz, nxn;
    if (t < 127) {
      int tp2 = rev ? (126 - t) : (t + 1);
      const u16* gp2 = G + (base + (long)tp2 * stride) * 192 + d0;
      nxr = *(const uint2*)(gp2);
      nxz = *(const uint2*)(gp2 + 64);
      nxn = *(const uint2*)(gp2 + 128);
    }

    // ---- MFMA phase: HG = h @ W_hh^T + b_hh ----
    s8v a0 = *(const s8v*)(&ha[col][kq * 8]);
    s8v a1 = *(const s8v*)(&ha[col][32 + kq * 8]);
    #pragma unroll
    for (int j = 0; j < 3; j++) {
      f4v acc = biasf[j];
      acc = __builtin_amdgcn_mfma_f32_16x16x32_bf16(a0, bfrag0[j], acc, 0, 0, 0);
      acc = __builtin_amdgcn_mfma_f32_16x16x32_bf16(a1, bfrag1[j], acc, 0, 0, 0);
      int g = wave * 48 + j * 16 + col;
      hgl[kq * 4 + 0][g] = acc[0];
      hgl[kq * 4 + 1][g] = acc[1];
      hgl[kq * 4 + 2][g] = acc[2];
      hgl[kq * 4 + 3][g] = acc[3];
    }
    __syncthreads();

    // ---- gate phase ----
    f4v hr = *(const f4v*)(&hgl[gs][d0]);
    f4v hz = *(const f4v*)(&hgl[gs][64 + d0]);
    f4v hn = *(const f4v*)(&hgl[gs][128 + d0]);
    u16* px = (u16*)&xr; u16* pz = (u16*)&xz; u16* pn = (u16*)&xn;
    ushort4 hv; u16* hvp = (u16*)&hv;
    #pragma unroll
    for (int i = 0; i < 4; i++) {
      float r = sigf(bf2f(px[i]) + hr[i]);
      float z = sigf(bf2f(pz[i]) + hz[i]);
      float n = tanh_fast(bf2f(pn[i]) + r * hn[i]);
      float h = (1.f - z) * n + z * hold[i];
      hold[i] = h;
      hvp[i] = f2bf(h);
    }
    *(ushort4*)(&ha[gs][d0]) = hv;                       // h for next MFMA (A layout)
    long posc = base + (long)(rev ? (127 - t) : t) * stride;
    *(ushort4*)(Hs + posc * 64 + d0) = hv;               // stream h out
    if (t < 127) { xr = nxr; xz = nxz; xn = nxn; }
    __syncthreads();
  }
}

// ---------------------------------------------------------------------------
// Kernel 3: out[b,c,h,w] = bo[c] + Wo[c,:] . (sum_dirs h)/4   (fp32 out)
// MFMA: M=64 spatial, N=192 channels, K=64. C rows = consecutive spatial ->
// float4 stores into channel-first output.
// ---------------------------------------------------------------------------
__global__ __launch_bounds__(256) void k_out(const u16* __restrict__ Hall, const float* __restrict__ Wo,
                                             const float* __restrict__ bo, float* __restrict__ out){
  __shared__ u16 hs4[64][72];
  const int tid = threadIdx.x;
  const int wave = tid >> 6, lane = tid & 63;
  const int col = lane & 15, kq = lane >> 4;
  const long s0 = (long)blockIdx.x * 64;
  const int b   = (int)(s0 >> 14);
  const int hw0 = (int)(s0 & 16383);

  s8v bfrag[3][2]; f4v biasf[3];
  #pragma unroll
  for (int j = 0; j < 3; j++) {
    int g = wave * 48 + j * 16 + col;
    bfrag[j][0] = load8_f32_as_bf16(Wo + g * 64 + kq * 8);
    bfrag[j][1] = load8_f32_as_bf16(Wo + g * 64 + 32 + kq * 8);
    float bb = bo[g];
    biasf[j] = (f4v){bb, bb, bb, bb};
  }

  // Stage (sum of 4 direction h)/4 as bf16
  for (int idx = tid; idx < 64 * 16; idx += 256) {
    int sl = idx >> 4;
    int d4 = (idx & 15) * 4;
    long p = (s0 + sl) * 64 + d4;
    float a0 = 0.f, a1 = 0.f, a2 = 0.f, a3 = 0.f;
    #pragma unroll
    for (int dd = 0; dd < 4; dd++) {
      uint2 v = *(const uint2*)(Hall + dd * (NSp * 64) + p);
      u16* pv = (u16*)&v;
      a0 += bf2f(pv[0]); a1 += bf2f(pv[1]); a2 += bf2f(pv[2]); a3 += bf2f(pv[3]);
    }
    ushort4 o;
    o.x = f2bf(0.25f * a0); o.y = f2bf(0.25f * a1);
    o.z = f2bf(0.25f * a2); o.w = f2bf(0.25f * a3);
    *(ushort4*)(&hs4[sl][d4]) = o;
  }
  __syncthreads();

  f4v acc[4][3];
  #pragma unroll
  for (int m = 0; m < 4; m++)
    #pragma unroll
    for (int j = 0; j < 3; j++) acc[m][j] = biasf[j];

  #pragma unroll
  for (int kc = 0; kc < 2; kc++) {
    #pragma unroll
    for (int m = 0; m < 4; m++) {
      s8v a = *(const s8v*)(&hs4[m * 16 + col][kc * 32 + kq * 8]);
      #pragma unroll
      for (int j = 0; j < 3; j++)
        acc[m][j] = __builtin_amdgcn_mfma_f32_16x16x32_bf16(a, bfrag[j][kc], acc[m][j], 0, 0, 0);
    }
  }

  #pragma unroll
  for (int j = 0; j < 3; j++) {
    int g = wave * 48 + j * 16 + col;
    #pragma unroll
    for (int m = 0; m < 4; m++) {
      float4 v;
      v.x = acc[m][j][0]; v.y = acc[m][j][1];
      v.z = acc[m][j][2]; v.w = acc[m][j][3];
      long addr = ((long)(b * 192 + g) << 14) + hw0 + m * 16 + kq * 4;
      *(float4*)(out + addr) = v;
    }
  }
}

// ---------------------------------------------------------------------------
extern "C" void kernel_launch(void* const* d_in, const int* in_sizes, int n_in,
                              void* d_out, int out_size, void* d_ws, size_t ws_size,
                              hipStream_t stream){
  const float* x    = (const float*)d_in[0];
  const float* Wi   = (const float*)d_in[1];
  const float* bi   = (const float*)d_in[2];
  const float* W_ih = (const float*)d_in[3];
  const float* W_hh = (const float*)d_in[4];
  const float* b_ih = (const float*)d_in[5];
  const float* b_hh = (const float*)d_in[6];
  const float* Wo   = (const float*)d_in[7];
  const float* bo   = (const float*)d_in[8];

  char* ws = (char*)d_ws;
  u16*   wcomb = (u16*)(ws);                       // 192*192 bf16        = 73728 B
  float* bcomb = (float*)(ws + 73728);             // 192 fp32            = 768 B
  u16*   G     = (u16*)(ws + 74496);               // 131072*192 bf16     = 50331648 B
  u16*   Hall  = (u16*)(ws + 50406144);            // 4*131072*64 bf16    = 67108864 B
                                                   // total               = 117515008 B

  k_wcomb<<<145,  256, 0, stream>>>(Wi, bi, W_ih, b_ih, wcomb, bcomb);
  k_gates<<<2048, 256, 0, stream>>>(x, wcomb, bcomb, G);
  k_scan <<<256,  256, 0, stream>>>(G, W_hh, b_hh, Hall);
  k_out  <<<2048, 256, 0, stream>>>(Hall, Wo, bo, (float*)d_out);
}